// Round 5
// baseline (177.274 us; speedup 1.0000x reference)
//
#include <hip/hip_runtime.h>

// Problem constants (from reference): B=4096, N_ELEM=2048, N_NODES=1024, E2=4096
#define B_SAMPLES 4096
#define N_ELEM    2048
#define N_NODES   1024
#define E2        4096
#define BLOCK     256
#define SLOTS     32                     // max entries/node (Poisson mean 4; P(>=32) ~ 1e-15)
#define S         4                      // samples per main block
#define MAIN_BLOCKS (B_SAMPLES / S)      // 1024

// Workspace layout (bytes):
//   [0, 4K)        : cnt[N_NODES]          (int)
//   [4K, 4K+512K)  : ell[SLOTS][N_NODES]   (float4 {wx, wy, bitcast(eid), pad})
#define WS_CNT_OFF   0
#define WS_ELL_OFF   4096

// ---------------------------------------------------------------------------
// Setup A: zero ELL table + counters. 128 blocks x 256 = one float4 each.
// ---------------------------------------------------------------------------
__global__ __launch_bounds__(BLOCK) void neq_zero_kernel(
    float4* __restrict__ ell, int* __restrict__ cnt)
{
    const int i = blockIdx.x * BLOCK + threadIdx.x;      // 0 .. 32767
    ell[i] = make_float4(0.f, 0.f, 0.f, 0.f);
    if (i < N_NODES) cnt[i] = 0;
}

// ---------------------------------------------------------------------------
// Setup B: build transposed-ELL via global atomics (order-independent sum).
// ---------------------------------------------------------------------------
__global__ __launch_bounds__(BLOCK) void neq_build_kernel(
    const float* __restrict__ vecs, const int* __restrict__ node_ids,
    const int* __restrict__ elem_ids, int* __restrict__ cnt,
    float4* __restrict__ ell)
{
    const int j = blockIdx.x * BLOCK + threadIdx.x;      // 0 .. E2-1
    int nid = node_ids[j];
    int eid = elem_ids[j];
    float2 v = ((const float2*)vecs)[j];
    int slot = atomicAdd(&cnt[nid], 1);                  // device-scope
    if (slot < SLOTS) {
        ell[slot * N_NODES + nid] = make_float4(v.x, v.y, __int_as_float(eid), 0.f);
    }
}

// ---------------------------------------------------------------------------
// Main: one block per S samples. axial sample-interleaved in LDS; q+r hoisted
// pre-barrier (HBM overlap); ELL row k+1 register-prefetched; fused final
// reduce via one global atomic per block.
// ---------------------------------------------------------------------------
__global__ __launch_bounds__(BLOCK, 4) void neq_main_kernel(
    const float* __restrict__ EA, const float* __restrict__ e,
    const float* __restrict__ q,  const float* __restrict__ r,
    const int* __restrict__ cnt, const float4* __restrict__ ell,
    float* __restrict__ out)
{
    __shared__ float4 axial4[N_ELEM];    // 32 KiB: axial4[eid] = {s0,s1,s2,s3}
    __shared__ float red[BLOCK / 64];

    const int b0 = blockIdx.x * S;
    const int t = threadIdx.x;

    // ---- phase 1: axial4[eid] = EA*e for 4 samples ----
#pragma unroll
    for (int i = 0; i < N_ELEM / BLOCK; ++i) {           // 8 iters
        int eid = t + i * BLOCK;
        float4 p;
        const float* EAp = EA + (size_t)b0 * N_ELEM + eid;
        const float* ep  = e  + (size_t)b0 * N_ELEM + eid;
        p.x = EAp[0 * N_ELEM] * ep[0 * N_ELEM];
        p.y = EAp[1 * N_ELEM] * ep[1 * N_ELEM];
        p.z = EAp[2 * N_ELEM] * ep[2 * N_ELEM];
        p.w = EAp[3 * N_ELEM] * ep[3 * N_ELEM];
        axial4[eid] = p;
    }

    // ---- hoist q+r (issues alongside phase-1 HBM stream; folded to 32 VGPRs) ----
    float2 qr[S][4];
#pragma unroll
    for (int s = 0; s < S; ++s) {
        const float2* q2 = (const float2*)(q + (size_t)(b0 + s) * N_NODES * 2);
        const float2* r2 = (const float2*)(r + (size_t)(b0 + s) * N_NODES * 2);
#pragma unroll
        for (int i = 0; i < 4; ++i) {
            int n = t + i * BLOCK;
            float2 qv = q2[n];
            float2 rv = r2[n];
            qr[s][i] = make_float2(qv.x + rv.x, qv.y + rv.y);
        }
    }

    // per-node counts (thread owns nodes t, t+256, t+512, t+768)
    int c0 = min(cnt[t], SLOTS);
    int c1 = min(cnt[t + 256], SLOTS);
    int c2 = min(cnt[t + 512], SLOTS);
    int c3 = min(cnt[t + 768], SLOTS);
    int kmax = max(max(c0, c1), max(c2, c3));
    __syncthreads();

    // ---- phase 2: gather with k+1 register prefetch (zero-padded => branchless) ----
    float accx[4][S] = {};
    float accy[4][S] = {};
    if (kmax > 0) {
        float4 pk[4];
#pragma unroll
        for (int i = 0; i < 4; ++i) pk[i] = ell[t + i * BLOCK];
        for (int k = 0; k < kmax; ++k) {
            float4 nx[4];
            const float4* nrow = ell + min(k + 1, SLOTS - 1) * N_NODES + t;
#pragma unroll
            for (int i = 0; i < 4; ++i) nx[i] = nrow[i * BLOCK];   // prefetch k+1
#pragma unroll
            for (int i = 0; i < 4; ++i) {
                int eid = __float_as_int(pk[i].z);
                float4 ax = axial4[eid];                 // one ds_read_b128
                accx[i][0] += ax.x * pk[i].x;  accy[i][0] += ax.x * pk[i].y;
                accx[i][1] += ax.y * pk[i].x;  accy[i][1] += ax.y * pk[i].y;
                accx[i][2] += ax.z * pk[i].x;  accy[i][2] += ax.z * pk[i].y;
                accx[i][3] += ax.w * pk[i].x;  accy[i][3] += ax.w * pk[i].y;
            }
#pragma unroll
            for (int i = 0; i < 4; ++i) pk[i] = nx[i];
        }
    }

    // ---- phase 3: residual & sum of squares (pure compute, q+r already in regs) ----
    float acc = 0.f;
#pragma unroll
    for (int s = 0; s < S; ++s) {
#pragma unroll
        for (int i = 0; i < 4; ++i) {
            float x = accx[i][s] - qr[s][i].x;
            float y = accy[i][s] - qr[s][i].y;
            acc += x * x + y * y;
        }
    }

    // ---- wave + block reduce, one global atomic per block ----
#pragma unroll
    for (int off = 32; off > 0; off >>= 1)
        acc += __shfl_down(acc, off, 64);
    if ((t & 63) == 0) red[t >> 6] = acc;
    __syncthreads();
    if (t == 0) {
        const float inv_n = 1.0f / (float)((size_t)B_SAMPLES * N_NODES * 2);
        atomicAdd(out, (red[0] + red[1] + red[2] + red[3]) * inv_n);
    }
}

extern "C" void kernel_launch(void* const* d_in, const int* in_sizes, int n_in,
                              void* d_out, int out_size, void* d_ws, size_t ws_size,
                              hipStream_t stream) {
    const float* EA       = (const float*)d_in[0];
    const float* e        = (const float*)d_in[1];
    const float* q        = (const float*)d_in[2];
    const float* r        = (const float*)d_in[3];
    const float* vecs     = (const float*)d_in[4];
    const int*   node_ids = (const int*)d_in[5];
    const int*   elem_ids = (const int*)d_in[6];

    char* ws = (char*)d_ws;
    int*    cnt = (int*)(ws + WS_CNT_OFF);
    float4* ell = (float4*)(ws + WS_ELL_OFF);

    hipMemsetAsync(d_out, 0, sizeof(float), stream);     // accumulator for fused reduce

    neq_zero_kernel<<<(SLOTS * N_NODES) / BLOCK, BLOCK, 0, stream>>>(ell, cnt);
    neq_build_kernel<<<E2 / BLOCK, BLOCK, 0, stream>>>(
        vecs, node_ids, elem_ids, cnt, ell);
    neq_main_kernel<<<MAIN_BLOCKS, BLOCK, 0, stream>>>(
        EA, e, q, r, cnt, ell, (float*)d_out);
}

// Round 6
// 166.561 us; speedup vs baseline: 1.0643x; 1.0643x over previous
//
#include <hip/hip_runtime.h>

// Problem constants (from reference): B=4096, N_ELEM=2048, N_NODES=1024, E2=4096
#define B_SAMPLES 4096
#define N_ELEM    2048
#define N_NODES   1024
#define E2        4096
#define BLOCK     512                    // 8 waves/block; 4 blocks/CU (LDS) = 32 waves = 100% cap
#define SLOTS     32                     // max entries/node (Poisson mean 4; P(>=32) ~ 1e-15)
#define S         4                      // samples per main block
#define NPT       (N_NODES / BLOCK)      // 2 nodes per thread
#define MAIN_BLOCKS (B_SAMPLES / S)      // 1024

// Workspace layout (bytes):
//   [0, 4K)        : cnt[N_NODES]          (int)
//   [4K, 4K+512K)  : ell[SLOTS][N_NODES]   (float4 {wx, wy, bitcast(eid), pad})
#define WS_CNT_OFF   0
#define WS_ELL_OFF   4096

// ---------------------------------------------------------------------------
// Setup A: zero ELL table + counters.
// ---------------------------------------------------------------------------
__global__ __launch_bounds__(256) void neq_zero_kernel(
    float4* __restrict__ ell, int* __restrict__ cnt)
{
    const int i = blockIdx.x * 256 + threadIdx.x;        // 0 .. 32767
    ell[i] = make_float4(0.f, 0.f, 0.f, 0.f);
    if (i < N_NODES) cnt[i] = 0;
}

// ---------------------------------------------------------------------------
// Setup B: build transposed-ELL via global atomics (order-independent sum).
// ---------------------------------------------------------------------------
__global__ __launch_bounds__(256) void neq_build_kernel(
    const float* __restrict__ vecs, const int* __restrict__ node_ids,
    const int* __restrict__ elem_ids, int* __restrict__ cnt,
    float4* __restrict__ ell)
{
    const int j = blockIdx.x * 256 + threadIdx.x;        // 0 .. E2-1
    int nid = node_ids[j];
    int eid = elem_ids[j];
    float2 v = ((const float2*)vecs)[j];
    int slot = atomicAdd(&cnt[nid], 1);                  // device-scope
    if (slot < SLOTS) {
        ell[slot * N_NODES + nid] = make_float4(v.x, v.y, __int_as_float(eid), 0.f);
    }
}

// ---------------------------------------------------------------------------
// Main: 512 threads, one block per S=4 samples, 2 nodes/thread. axial
// sample-interleaved in LDS (one ds_read_b128 per gather); count-guarded
// gather loads (saves ~3x padded-row L2 traffic); no atomics in hot path;
// fused final reduce via one global atomic per block.
// ---------------------------------------------------------------------------
__global__ __launch_bounds__(BLOCK, 4) void neq_main_kernel(
    const float* __restrict__ EA, const float* __restrict__ e,
    const float* __restrict__ q,  const float* __restrict__ r,
    const int* __restrict__ cnt, const float4* __restrict__ ell,
    float* __restrict__ out)
{
    __shared__ float4 axial4[N_ELEM];    // 32 KiB: axial4[eid] = {s0,s1,s2,s3}
    __shared__ float red[BLOCK / 64];

    const int b0 = blockIdx.x * S;
    const int t = threadIdx.x;

    // ---- phase 1: axial4[eid] = EA*e for 4 samples (coalesced dword loads) ----
#pragma unroll
    for (int i = 0; i < N_ELEM / BLOCK; ++i) {           // 4 iters
        int eid = t + i * BLOCK;
        float4 p;
        const float* EAp = EA + (size_t)b0 * N_ELEM + eid;
        const float* ep  = e  + (size_t)b0 * N_ELEM + eid;
        p.x = EAp[0 * N_ELEM] * ep[0 * N_ELEM];
        p.y = EAp[1 * N_ELEM] * ep[1 * N_ELEM];
        p.z = EAp[2 * N_ELEM] * ep[2 * N_ELEM];
        p.w = EAp[3 * N_ELEM] * ep[3 * N_ELEM];
        axial4[eid] = p;
    }

    // per-node counts (thread owns nodes t and t+512)
    int c0 = min(cnt[t], SLOTS);
    int c1 = min(cnt[t + BLOCK], SLOTS);
    int kmax = max(c0, c1);
    __syncthreads();

    // ---- phase 2: gather, count-guarded (exec-masked) loads ----
    float accx[NPT][S] = {};
    float accy[NPT][S] = {};
    for (int k = 0; k < kmax; ++k) {
        const float4* row = ell + k * N_NODES + t;
#pragma unroll
        for (int i = 0; i < NPT; ++i) {
            int ci = (i == 0) ? c0 : c1;
            if (k < ci) {
                float4 pk = row[i * BLOCK];              // coalesced 16B (masked)
                int eid = __float_as_int(pk.z);
                float4 ax = axial4[eid];                 // one ds_read_b128
                accx[i][0] += ax.x * pk.x;  accy[i][0] += ax.x * pk.y;
                accx[i][1] += ax.y * pk.x;  accy[i][1] += ax.y * pk.y;
                accx[i][2] += ax.z * pk.x;  accy[i][2] += ax.z * pk.y;
                accx[i][3] += ax.w * pk.x;  accy[i][3] += ax.w * pk.y;
            }
        }
    }

    // ---- phase 3: residual & sum of squares (q/r loaded late: low pressure) ----
    float acc = 0.f;
#pragma unroll
    for (int s = 0; s < S; ++s) {
        const float2* q2 = (const float2*)(q + (size_t)(b0 + s) * N_NODES * 2);
        const float2* r2 = (const float2*)(r + (size_t)(b0 + s) * N_NODES * 2);
#pragma unroll
        for (int i = 0; i < NPT; ++i) {
            int n = t + i * BLOCK;
            float2 qv = q2[n];
            float2 rv = r2[n];
            float x = accx[i][s] - qv.x - rv.x;
            float y = accy[i][s] - qv.y - rv.y;
            acc += x * x + y * y;
        }
    }

    // ---- wave + block reduce, one global atomic per block ----
#pragma unroll
    for (int off = 32; off > 0; off >>= 1)
        acc += __shfl_down(acc, off, 64);
    if ((t & 63) == 0) red[t >> 6] = acc;
    __syncthreads();
    if (t == 0) {
        float s = 0.f;
#pragma unroll
        for (int w = 0; w < BLOCK / 64; ++w) s += red[w];
        const float inv_n = 1.0f / (float)((size_t)B_SAMPLES * N_NODES * 2);
        atomicAdd(out, s * inv_n);
    }
}

extern "C" void kernel_launch(void* const* d_in, const int* in_sizes, int n_in,
                              void* d_out, int out_size, void* d_ws, size_t ws_size,
                              hipStream_t stream) {
    const float* EA       = (const float*)d_in[0];
    const float* e        = (const float*)d_in[1];
    const float* q        = (const float*)d_in[2];
    const float* r        = (const float*)d_in[3];
    const float* vecs     = (const float*)d_in[4];
    const int*   node_ids = (const int*)d_in[5];
    const int*   elem_ids = (const int*)d_in[6];

    char* ws = (char*)d_ws;
    int*    cnt = (int*)(ws + WS_CNT_OFF);
    float4* ell = (float4*)(ws + WS_ELL_OFF);

    hipMemsetAsync(d_out, 0, sizeof(float), stream);     // accumulator for fused reduce

    neq_zero_kernel<<<(SLOTS * N_NODES) / 256, 256, 0, stream>>>(ell, cnt);
    neq_build_kernel<<<E2 / 256, 256, 0, stream>>>(
        vecs, node_ids, elem_ids, cnt, ell);
    neq_main_kernel<<<MAIN_BLOCKS, BLOCK, 0, stream>>>(
        EA, e, q, r, cnt, ell, (float*)d_out);
}